// Round 2
// baseline (1572.132 us; speedup 1.0000x reference)
//
#include <hip/hip_runtime.h>
#include <hip/hip_bf16.h>
#include <math.h>

typedef __hip_bfloat16 bf16;
typedef __attribute__((ext_vector_type(8))) __bf16 bf16x8;
typedef __attribute__((ext_vector_type(4))) float f32x4;
typedef __attribute__((ext_vector_type(4))) unsigned u32x4;

#define NB 64
#define NTOK 256
#define CDIM 1024
#define NH 16
#define DH 64
#define DFF 4096
#define MROWS (NB * NTOK)  // 16384

// fast tanh-approx gelu in sigmoid form: one v_exp instead of a tanhf libcall chain
__device__ __forceinline__ float gelu_f(float x) {
    float t = 1.5957691216057308f * (x + 0.044715f * x * x * x);
    return x / (1.0f + __expf(-t));
}

// async 16B global->LDS (gfx950). LDS dest must be wave-uniform base; HW adds lane*16.
__device__ __forceinline__ void gload_lds16(const void* g, void* l) {
    __builtin_amdgcn_global_load_lds((const __attribute__((address_space(1))) void*)g,
                                     (__attribute__((address_space(3))) void*)l,
                                     16, 0, 0);
}

// ------------- transpose + downcast: in fp32 [R][C] -> out bf16 [C][R] -------------
__global__ void transpose_f32_bf16(const float* __restrict__ in, bf16* __restrict__ out,
                                   int R, int Cc) {
    __shared__ bf16 tile[32][33];
    int c0 = blockIdx.x * 32, r0 = blockIdx.y * 32;
    int t = threadIdx.x;
    int r = t >> 5, c = t & 31;
#pragma unroll
    for (int i = 0; i < 4; i++)
        tile[r + i * 8][c] = (bf16)in[(size_t)(r0 + r + i * 8) * Cc + c0 + c];
    __syncthreads();
#pragma unroll
    for (int i = 0; i < 4; i++)
        out[(size_t)(c0 + r + i * 8) * R + r0 + c] = tile[c][r + i * 8];
}

// ------------- layernorm: fp32 in -> bf16 out; one row (C=1024) per block -------------
__global__ __launch_bounds__(256) void ln_kernel(const float* __restrict__ xin,
                                                 const float* __restrict__ g,
                                                 const float* __restrict__ b,
                                                 bf16* __restrict__ outp) {
    __shared__ float red[8];
    int row = blockIdx.x, t = threadIdx.x;
    float4 v = ((const float4*)(xin + (size_t)row * CDIM))[t];
    float s = v.x + v.y + v.z + v.w;
    float q = v.x * v.x + v.y * v.y + v.z * v.z + v.w * v.w;
#pragma unroll
    for (int off = 32; off > 0; off >>= 1) {
        s += __shfl_down(s, off);
        q += __shfl_down(q, off);
    }
    int wave = t >> 6;
    if ((t & 63) == 0) { red[wave] = s; red[4 + wave] = q; }
    __syncthreads();
    float st = red[0] + red[1] + red[2] + red[3];
    float qt = red[4] + red[5] + red[6] + red[7];
    float mu = st * (1.0f / CDIM);
    float rstd = rsqrtf(qt * (1.0f / CDIM) - mu * mu + 1e-5f);
    float4 gv = ((const float4*)g)[t];
    float4 bv = ((const float4*)b)[t];
    bf16* orow = outp + (size_t)row * CDIM + t * 4;
    orow[0] = (bf16)((v.x - mu) * rstd * gv.x + bv.x);
    orow[1] = (bf16)((v.y - mu) * rstd * gv.y + bv.y);
    orow[2] = (bf16)((v.z - mu) * rstd * gv.z + bv.z);
    orow[3] = (bf16)((v.w - mu) * rstd * gv.w + bv.w);
}

// ------------- bias gather: biasq[h][q][k] = rpb[idx[q*256+k]*16+h] (fp32) -------------
__global__ void biasq_kernel(const int* __restrict__ idx, const float* __restrict__ rpb,
                             float* __restrict__ bq) {
    int e = blockIdx.x * 256 + threadIdx.x;
    int k = e & 255, q = (e >> 8) & 255, h = e >> 16;
    bq[e] = rpb[idx[q * 256 + k] * NH + h];
}

// ------------- GEMM: C[M,N] = A[M,K] @ Bt[N,K]^T  (A,Bt bf16; fp32 acc) -------------
// T3 minimum-2-phase: double-buffered LDS, global_load_lds(16B) for NEXT K-step issued
// BEFORE compute of current step; ONE __syncthreads (vmcnt(0)+barrier) per K-step.
// mode 0: +bias, q*=0.125 -> scatter to bf16 qkv buffer [3][Bc][H][N][DH] (stride qstride)
// mode 2: +bias, gelu -> bf16 row-major
// mode 3: +bias, +fp32 resid -> fp32 row-major (outp may alias resid; same-thread RMW)
__global__ __launch_bounds__(256) void gemm_bt_kernel(
    const bf16* __restrict__ Abf, const bf16* __restrict__ Btbf,
    const float* __restrict__ bias, const float* resid,
    void* outp, size_t qstride, int M, int N, int K, int mode) {
    __shared__ __align__(16) u32x4 As[2][1024];  // 32 KB
    __shared__ __align__(16) u32x4 Bs[2][1024];  // 32 KB
    const unsigned short* A = (const unsigned short*)Abf;
    const unsigned short* Bt = (const unsigned short*)Btbf;
    int tid = threadIdx.x;
    int wave = tid >> 6, lane = tid & 63;
    int quad = lane >> 4, lr = lane & 15;
    int wm = (wave >> 1) << 6, wn = (wave & 1) << 6;
    size_t row0 = (size_t)blockIdx.y << 7;
    size_t col0 = (size_t)blockIdx.x << 7;
    const unsigned short* Ag = A + row0 * K;
    const unsigned short* Bg = Bt + col0 * K;
    f32x4 acc[4][4] = {};

    const int swave = tid & ~63;  // wave-uniform LDS slot base

    // stage one 128x64 (A) + 128x64 (B) K-step into buffer `buf`
    auto stage = [&](int buf, int k0) {
#pragma unroll
        for (int ii = 0; ii < 4; ii++) {
            int ch = ii * 256 + tid;
            int kk = ch >> 7, r = ch & 127;
            size_t goff = (size_t)r * K + (k0 + kk * 8);
            gload_lds16(Ag + goff, (void*)&As[buf][ii * 256 + swave]);
            gload_lds16(Bg + goff, (void*)&Bs[buf][ii * 256 + swave]);
        }
    };

    stage(0, 0);
    __syncthreads();  // drain vmcnt(0): buffer 0 ready
    int cur = 0;
    for (int k0 = 0; k0 < K; k0 += 64) {
        if (k0 + 64 < K) stage(cur ^ 1, k0 + 64);  // async: in flight during compute
#pragma unroll
        for (int ks = 0; ks < 2; ks++) {
            bf16x8 af[4], bfr[4];
#pragma unroll
            for (int i = 0; i < 4; i++) {
                af[i]  = __builtin_bit_cast(bf16x8, As[cur][(ks * 4 + quad) * 128 + wm + i * 16 + lr]);
                bfr[i] = __builtin_bit_cast(bf16x8, Bs[cur][(ks * 4 + quad) * 128 + wn + i * 16 + lr]);
            }
#pragma unroll
            for (int i = 0; i < 4; i++)
#pragma unroll
                for (int j = 0; j < 4; j++)
                    acc[i][j] = __builtin_amdgcn_mfma_f32_16x16x32_bf16(af[i], bfr[j],
                                                                        acc[i][j], 0, 0, 0);
        }
        __syncthreads();  // vmcnt(0): next buffer complete; all waves done reading cur
        cur ^= 1;
    }

    float bc[4];
#pragma unroll
    for (int j = 0; j < 4; j++) bc[j] = bias[col0 + wn + j * 16 + lr];
#pragma unroll
    for (int i = 0; i < 4; i++) {
#pragma unroll
        for (int r = 0; r < 4; r++) {
            int R = (int)row0 + wm + i * 16 + quad * 4 + r;
#pragma unroll
            for (int j = 0; j < 4; j++) {
                int Cc = (int)col0 + wn + j * 16 + lr;
                float val = acc[i][j][r] + bc[j];
                if (mode == 0) {
                    int t3 = Cc >> 10, rem = Cc & 1023;
                    int head = rem >> 6, d = rem & 63;
                    int lb = R >> 8, nn = R & 255;
                    if (t3 == 0) val *= 0.125f;  // Dh^-0.5
                    ((bf16*)outp)[(size_t)t3 * qstride +
                                  ((size_t)((lb << 4) + head) * NTOK + nn) * DH + d] = (bf16)val;
                } else if (mode == 2) {
                    ((bf16*)outp)[(size_t)R * N + Cc] = (bf16)gelu_f(val);
                } else {
                    val += resid[(size_t)R * N + Cc];
                    ((float*)outp)[(size_t)R * N + Cc] = val;
                }
            }
        }
    }
}

// ------------- MFMA flash attention: one workgroup per (b,h), wave = 64 queries ------
// LDS (64 KB total): K half (128 keys x 64d, chunk-swizzled), V^T half (packed 2k/word,
// chunk-swizzled), per-wave P/Q scratch (64q x 64, chunk-swizzled).
__global__ __launch_bounds__(256, 2) void attn_mfma(
    const bf16* __restrict__ qkv, const float* __restrict__ biasq,
    bf16* __restrict__ outp, size_t qstride) {
    __shared__ u32x4 Ks4[1024];      // 16 KB
    __shared__ unsigned Vt32[4096];  // 16 KB
    __shared__ u32x4 PQ4[2048];      // 32 KB

    int bh = blockIdx.x, lb = bh >> 4, h = bh & 15;
    int tid = threadIdx.x, wave = tid >> 6, lane = tid & 63;
    int quad = lane >> 4, lr = lane & 15;
    int wq = wave << 6;
    const unsigned short* qg = (const unsigned short*)qkv + (size_t)bh * 16384;

    // ---- stage this wave's Q tile into its PQ region (wave-private), read A-frags ----
    u32x4* pqw = PQ4 + wave * 512;
#pragma unroll
    for (int it = 0; it < 8; it++) {
        int c = it * 64 + lane;
        int qrow = c >> 3, p = c & 7;
        pqw[qrow * 8 + (p ^ (qrow & 7))] =
            *(const u32x4*)(qg + (size_t)(wq + qrow) * 64 + p * 8);
    }
    bf16x8 qf[4][2];
#pragma unroll
    for (int i = 0; i < 4; i++)
#pragma unroll
        for (int ks = 0; ks < 2; ks++) {
            int qrow = i * 16 + lr;
            qf[i][ks] = __builtin_bit_cast(bf16x8,
                pqw[qrow * 8 + (((ks << 2) + quad) ^ (qrow & 7))]);
        }

    f32x4 o[4][4] = {};
    float mrun[4][4], lpart[4][4];
#pragma unroll
    for (int i = 0; i < 4; i++)
#pragma unroll
        for (int r = 0; r < 4; r++) { mrun[i][r] = -1e30f; lpart[i][r] = 0.f; }

    const float* bq = biasq + (size_t)h * 65536;  // [q][k]

    for (int half = 0; half < 2; half++) {
        __syncthreads();
        // stage K half (128 keys x 64 d), chunk-swizzled rows
        const unsigned short* kg = (const unsigned short*)qkv + qstride +
                                   (size_t)bh * 16384 + half * 8192;
#pragma unroll
        for (int it = 0; it < 4; it++) {
            int c = it * 256 + tid;
            int kr = c >> 3, p = c & 7;
            Ks4[kr * 8 + (p ^ (kr & 7))] = *(const u32x4*)(kg + (size_t)kr * 64 + p * 8);
        }
        // stage V^T half: Vt[d][k] packed 2 keys/word, chunk-swizzled
        const unsigned short* vg = (const unsigned short*)qkv + 2 * qstride +
                                   (size_t)bh * 16384 + half * 8192;
#pragma unroll
        for (int it = 0; it < 16; it++) {
            int idx = it * 256 + tid;
            int d = idx & 63, k2 = idx >> 6;  // k2: key pair 0..63
            unsigned lo = vg[(size_t)(2 * k2) * 64 + d];
            unsigned hi = vg[(size_t)(2 * k2 + 1) * 64 + d];
            int ck = k2 >> 2, w = k2 & 3;
            Vt32[d * 64 + ((ck ^ (d & 15)) << 2) + w] = lo | (hi << 16);
        }
        __syncthreads();

        for (int kb = 0; kb < 2; kb++) {
            // ---- S = Q K^T (64q x 64k) ----
            f32x4 s[4][4] = {};
#pragma unroll
            for (int ks = 0; ks < 2; ks++) {
                bf16x8 kf[4];
#pragma unroll
                for (int j = 0; j < 4; j++) {
                    int kr = kb * 64 + j * 16 + lr;
                    kf[j] = __builtin_bit_cast(bf16x8,
                        Ks4[kr * 8 + (((ks << 2) + quad) ^ (kr & 7))]);
                }
#pragma unroll
                for (int i = 0; i < 4; i++)
#pragma unroll
                    for (int j = 0; j < 4; j++)
                        s[i][j] = __builtin_amdgcn_mfma_f32_16x16x32_bf16(
                            qf[i][ks], kf[j], s[i][j], 0, 0, 0);
            }
            // ---- bias + online softmax (C-layout: row q = quad*4+r, col k = j*16+lr) ----
            int kglob = half * 128 + kb * 64;
#pragma unroll
            for (int i = 0; i < 4; i++) {
#pragma unroll
                for (int r = 0; r < 4; r++) {
                    int q = wq + i * 16 + quad * 4 + r;
                    const float* brow = bq + (size_t)q * 256 + kglob + lr;
                    float v0 = s[i][0][r] + brow[0];
                    float v1 = s[i][1][r] + brow[16];
                    float v2 = s[i][2][r] + brow[32];
                    float v3 = s[i][3][r] + brow[48];
                    float mx = fmaxf(fmaxf(v0, v1), fmaxf(v2, v3));
                    mx = fmaxf(mx, __shfl_xor(mx, 1));
                    mx = fmaxf(mx, __shfl_xor(mx, 2));
                    mx = fmaxf(mx, __shfl_xor(mx, 4));
                    mx = fmaxf(mx, __shfl_xor(mx, 8));
                    float mnew = fmaxf(mrun[i][r], mx);
                    float alpha = __expf(mrun[i][r] - mnew);
                    mrun[i][r] = mnew;
                    v0 = __expf(v0 - mnew);
                    v1 = __expf(v1 - mnew);
                    v2 = __expf(v2 - mnew);
                    v3 = __expf(v3 - mnew);
                    lpart[i][r] = lpart[i][r] * alpha + (v0 + v1 + v2 + v3);
                    s[i][0][r] = v0; s[i][1][r] = v1; s[i][2][r] = v2; s[i][3][r] = v3;
#pragma unroll
                    for (int dj = 0; dj < 4; dj++) o[i][dj][r] *= alpha;
                }
            }
            // ---- P -> wave-private LDS scratch in A-layout-friendly rows ----
            bf16* pqb = (bf16*)pqw;
#pragma unroll
            for (int i = 0; i < 4; i++)
#pragma unroll
                for (int r = 0; r < 4; r++) {
                    int ql = i * 16 + quad * 4 + r;
#pragma unroll
                    for (int j = 0; j < 4; j++) {
                        int col = j * 16 + lr;
                        int ck = col >> 3;
                        pqb[ql * 64 + ((ck ^ (ql & 7)) << 3) + (col & 7)] =
                            (bf16)s[i][j][r];
                    }
                }
            __syncthreads();  // orders mixed-width LDS writes before b128 reads
            // ---- O += P V ----
#pragma unroll
            for (int ks2 = 0; ks2 < 2; ks2++) {
                bf16x8 pf[4], vf[4];
#pragma unroll
                for (int i = 0; i < 4; i++) {
                    int ql = i * 16 + lr;
                    pf[i] = __builtin_bit_cast(bf16x8,
                        pqw[ql * 8 + (((ks2 << 2) + quad) ^ (ql & 7))]);
                }
#pragma unroll
                for (int dj = 0; dj < 4; dj++) {
                    int d = dj * 16 + lr;
                    int ck = kb * 8 + ks2 * 4 + quad;
                    vf[dj] = __builtin_bit_cast(bf16x8,
                        *(const u32x4*)(Vt32 + d * 64 + ((ck ^ (d & 15)) << 2)));
                }
#pragma unroll
                for (int i = 0; i < 4; i++)
#pragma unroll
                    for (int dj = 0; dj < 4; dj++)
                        o[i][dj] = __builtin_amdgcn_mfma_f32_16x16x32_bf16(
                            pf[i], vf[dj], o[i][dj], 0, 0, 0);
            }
        }
    }

    // ---- finalize: 1/l scale, store merged-heads bf16 ----
#pragma unroll
    for (int i = 0; i < 4; i++)
#pragma unroll
        for (int r = 0; r < 4; r++) {
            float lp = lpart[i][r];
            lp += __shfl_xor(lp, 1);
            lp += __shfl_xor(lp, 2);
            lp += __shfl_xor(lp, 4);
            lp += __shfl_xor(lp, 8);
            float inv = 1.0f / lp;
            int row = lb * 256 + wq + i * 16 + quad * 4 + r;
            bf16* orow = outp + (size_t)row * CDIM + h * DH;
#pragma unroll
            for (int dj = 0; dj < 4; dj++)
                orow[dj * 16 + lr] = (bf16)(o[i][dj][r] * inv);
        }
}

// ---------------- launch ----------------
extern "C" void kernel_launch(void* const* d_in, const int* in_sizes, int n_in,
                              void* d_out, int out_size, void* d_ws, size_t ws_size,
                              hipStream_t stream) {
    const float* x      = (const float*)d_in[0];
    const int*   rpi    = (const int*)d_in[1];
    const float* qkv_w  = (const float*)d_in[2];
    const float* qkv_b  = (const float*)d_in[3];
    const float* proj_w = (const float*)d_in[4];
    const float* proj_b = (const float*)d_in[5];
    const float* rpb    = (const float*)d_in[6];
    const float* ln1g   = (const float*)d_in[7];
    const float* ln1b   = (const float*)d_in[8];
    const float* ln2g   = (const float*)d_in[9];
    const float* ln2b   = (const float*)d_in[10];
    const float* fc1_w  = (const float*)d_in[11];
    const float* fc1_b  = (const float*)d_in[12];
    const float* fc2_w  = (const float*)d_in[13];
    const float* fc2_b  = (const float*)d_in[14];
    float* out = (float*)d_out;
    char* ws = (char*)d_ws;

    // --- fixed region: bf16 transposed weights + fp32 biasq (29,360,128 B) ---
    bf16* qkvT   = (bf16*)(ws);                 // 6,291,456
    bf16* projT  = (bf16*)(ws + 6291456ull);    // 2,097,152
    bf16* fc1T   = (bf16*)(ws + 8388608ull);    // 8,388,608
    bf16* fc2T   = (bf16*)(ws + 16777216ull);   // 8,388,608
    float* biasq = (float*)(ws + 25165824ull);  // 4,194,304
    const size_t fixed_end = 29360128ull;

    // --- adaptive chunk: per-row bytes = 2048 (hbuf) + 8192 (qkv or ff) ---
    long long avail = (long long)ws_size - (long long)fixed_end;
    long long rc = avail / 10240;
    rc &= ~255LL;
    if (rc < 256) rc = 256;
    if (rc > MROWS) rc = MROWS;
    const int Rc = (int)rc;
    bf16* hbuf   = (bf16*)(ws + fixed_end);                        // Rc*1024 bf16
    bf16* bigbuf = (bf16*)(ws + fixed_end + (size_t)Rc * 2048ull); // Rc*3072 or Rc*4096 bf16

    transpose_f32_bf16<<<dim3(3072 / 32, 1024 / 32), 256, 0, stream>>>(qkv_w, qkvT, 1024, 3072);
    transpose_f32_bf16<<<dim3(1024 / 32, 1024 / 32), 256, 0, stream>>>(proj_w, projT, 1024, 1024);
    transpose_f32_bf16<<<dim3(4096 / 32, 1024 / 32), 256, 0, stream>>>(fc1_w, fc1T, 1024, 4096);
    transpose_f32_bf16<<<dim3(1024 / 32, 4096 / 32), 256, 0, stream>>>(fc2_w, fc2T, 4096, 1024);
    biasq_kernel<<<4096, 256, 0, stream>>>(rpi, rpb, biasq);

    // --- phase A: LN1 -> qkv -> attention -> proj + residual ---
    for (int r0 = 0; r0 < MROWS; r0 += Rc) {
        int m = MROWS - r0 < Rc ? MROWS - r0 : Rc;
        size_t qs = (size_t)m * 1024;  // per-q/k/v stride in bf16 elems
        ln_kernel<<<m, 256, 0, stream>>>(x + (size_t)r0 * CDIM, ln1g, ln1b, hbuf);
        gemm_bt_kernel<<<dim3(3072 / 128, m / 128), 256, 0, stream>>>(
            hbuf, qkvT, qkv_b, nullptr, bigbuf, qs, m, 3072, 1024, 0);
        attn_mfma<<<(m / 256) * NH, 256, 0, stream>>>(bigbuf, biasq, hbuf, qs);
        gemm_bt_kernel<<<dim3(1024 / 128, m / 128), 256, 0, stream>>>(
            hbuf, projT, proj_b, x + (size_t)r0 * CDIM, out + (size_t)r0 * CDIM, 0,
            m, 1024, 1024, 3);
    }

    // --- phase B: LN2 -> fc1+gelu -> fc2 + residual ---
    for (int r0 = 0; r0 < MROWS; r0 += Rc) {
        int m = MROWS - r0 < Rc ? MROWS - r0 : Rc;
        ln_kernel<<<m, 256, 0, stream>>>(out + (size_t)r0 * CDIM, ln2g, ln2b, hbuf);
        gemm_bt_kernel<<<dim3(4096 / 128, m / 128), 256, 0, stream>>>(
            hbuf, fc1T, fc1_b, nullptr, bigbuf, 0, m, 4096, 1024, 2);
        gemm_bt_kernel<<<dim3(1024 / 128, m / 128), 256, 0, stream>>>(
            bigbuf, fc2T, fc2_b, out + (size_t)r0 * CDIM, out + (size_t)r0 * CDIM, 0,
            m, 1024, 4096, 3);
    }
}

// Round 3
// 1324.548 us; speedup vs baseline: 1.1869x; 1.1869x over previous
//
#include <hip/hip_runtime.h>
#include <hip/hip_bf16.h>
#include <math.h>

typedef __hip_bfloat16 bf16;
typedef __attribute__((ext_vector_type(8))) __bf16 bf16x8;
typedef __attribute__((ext_vector_type(4))) float f32x4;
typedef __attribute__((ext_vector_type(4))) unsigned u32x4;

#define NB 64
#define NTOK 256
#define CDIM 1024
#define NH 16
#define DH 64
#define DFF 4096
#define MROWS (NB * NTOK)  // 16384

// fast tanh-approx gelu in sigmoid form: one v_exp instead of a tanhf libcall chain
__device__ __forceinline__ float gelu_f(float x) {
    float t = 1.5957691216057308f * (x + 0.044715f * x * x * x);
    return x / (1.0f + __expf(-t));
}

// async 16B global->LDS (gfx950). LDS dest must be wave-uniform base; HW adds lane*16.
__device__ __forceinline__ void gload_lds16(const void* g, void* l) {
    __builtin_amdgcn_global_load_lds((const __attribute__((address_space(1))) void*)g,
                                     (__attribute__((address_space(3))) void*)l,
                                     16, 0, 0);
}

// ------------- transpose + downcast: in fp32 [R][C] -> out bf16 [C][R] -------------
__global__ void transpose_f32_bf16(const float* __restrict__ in, bf16* __restrict__ out,
                                   int R, int Cc) {
    __shared__ bf16 tile[32][33];
    int c0 = blockIdx.x * 32, r0 = blockIdx.y * 32;
    int t = threadIdx.x;
    int r = t >> 5, c = t & 31;
#pragma unroll
    for (int i = 0; i < 4; i++)
        tile[r + i * 8][c] = (bf16)in[(size_t)(r0 + r + i * 8) * Cc + c0 + c];
    __syncthreads();
#pragma unroll
    for (int i = 0; i < 4; i++)
        out[(size_t)(c0 + r + i * 8) * R + r0 + c] = tile[c][r + i * 8];
}

// ------------- layernorm: fp32 in -> bf16 out; one row (C=1024) per block -------------
__global__ __launch_bounds__(256) void ln_kernel(const float* __restrict__ xin,
                                                 const float* __restrict__ g,
                                                 const float* __restrict__ b,
                                                 bf16* __restrict__ outp) {
    __shared__ float red[8];
    int row = blockIdx.x, t = threadIdx.x;
    float4 v = ((const float4*)(xin + (size_t)row * CDIM))[t];
    float s = v.x + v.y + v.z + v.w;
    float q = v.x * v.x + v.y * v.y + v.z * v.z + v.w * v.w;
#pragma unroll
    for (int off = 32; off > 0; off >>= 1) {
        s += __shfl_down(s, off);
        q += __shfl_down(q, off);
    }
    int wave = t >> 6;
    if ((t & 63) == 0) { red[wave] = s; red[4 + wave] = q; }
    __syncthreads();
    float st = red[0] + red[1] + red[2] + red[3];
    float qt = red[4] + red[5] + red[6] + red[7];
    float mu = st * (1.0f / CDIM);
    float rstd = rsqrtf(qt * (1.0f / CDIM) - mu * mu + 1e-5f);
    float4 gv = ((const float4*)g)[t];
    float4 bv = ((const float4*)b)[t];
    bf16* orow = outp + (size_t)row * CDIM + t * 4;
    orow[0] = (bf16)((v.x - mu) * rstd * gv.x + bv.x);
    orow[1] = (bf16)((v.y - mu) * rstd * gv.y + bv.y);
    orow[2] = (bf16)((v.z - mu) * rstd * gv.z + bv.z);
    orow[3] = (bf16)((v.w - mu) * rstd * gv.w + bv.w);
}

// ------------- bias gather: biasq[h][q][k] = rpb[idx[q*256+k]*16+h] (fp32) -------------
__global__ void biasq_kernel(const int* __restrict__ idx, const float* __restrict__ rpb,
                             float* __restrict__ bq) {
    int e = blockIdx.x * 256 + threadIdx.x;
    int k = e & 255, q = (e >> 8) & 255, h = e >> 16;
    bq[e] = rpb[idx[q * 256 + k] * NH + h];
}

// ------------- GEMM: C[M,N] = A[M,K] @ Bt[N,K]^T  (A,Bt bf16; fp32 acc) -------------
// 256x256 tile, 8 waves, counted-vmcnt slab pipeline (T3+T4+T5):
//   K consumed in 32-wide slabs; 4 LDS slots x (A 16KB + B 16KB) = 128 KB.
//   iter s: issue slab s+2 (4 gload_lds) -> vmcnt(8) (slab s landed, s+1/s+2 STAY IN
//   FLIGHT across the barrier) -> s_barrier -> 32 MFMA under setprio(1).
// LDS layout per slab half: slot = kchunk*256 + row (k-chunk-major; conflict-free b128).
// mode 0: +bias, q*=0.125 -> scatter to bf16 qkv buffer [3][Bc][H][N][DH] (stride qstride)
// mode 2: +bias, gelu -> bf16 row-major
// mode 3: +bias, +fp32 resid -> fp32 row-major (outp may alias resid; same-thread RMW)
__global__ __launch_bounds__(512, 2) void gemm_bt_kernel(
    const bf16* __restrict__ Abf, const bf16* __restrict__ Btbf,
    const float* __restrict__ bias, const float* resid,
    void* outp, size_t qstride, int M, int N, int K, int mode) {
    __shared__ __align__(16) u32x4 SL[4][2][1024];  // 4 slots x (A,B) x 16KB = 128 KB
    const unsigned short* A = (const unsigned short*)Abf;
    const unsigned short* Bt = (const unsigned short*)Btbf;
    int tid = threadIdx.x;
    int wave = tid >> 6, lane = tid & 63;
    int quad = lane >> 4, lr = lane & 15;
    int wm = (wave >> 2) << 7;  // 0 / 128
    int wn = (wave & 3) << 6;   // 0 / 64 / 128 / 192
    size_t row0 = (size_t)blockIdx.y << 8;
    size_t col0 = (size_t)blockIdx.x << 8;
    const unsigned short* Ag = A + row0 * K;
    const unsigned short* Bg = Bt + col0 * K;
    f32x4 acc[8][4] = {};

    const int wbase = tid & ~63;  // wave-uniform LDS slot base

    // stage slab s (k in [s*32, s*32+32)): A half + B half, 4 gload_lds / thread
    auto stage = [&](int s) {
        int slot = s & 3;
        int kbase = s << 5;
#pragma unroll
        for (int it = 0; it < 2; it++) {
            int ch = it * 512 + tid;
            int kk = ch >> 8, r = ch & 255;
            gload_lds16(Ag + (size_t)r * K + (kbase + kk * 8),
                        (void*)&SL[slot][0][it * 512 + wbase]);
        }
#pragma unroll
        for (int it = 0; it < 2; it++) {
            int ch = it * 512 + tid;
            int kk = ch >> 8, r = ch & 255;
            gload_lds16(Bg + (size_t)r * K + (kbase + kk * 8),
                        (void*)&SL[slot][1][it * 512 + wbase]);
        }
    };

    int S = K >> 5;  // #slabs (>= 32 for all our shapes)
    stage(0);
    stage(1);
    for (int s = 0; s < S; s++) {
        if (s + 2 < S) {
            stage(s + 2);
            asm volatile("s_waitcnt vmcnt(8)" ::: "memory");  // slab s landed; 8 in flight
        } else if (s + 1 < S) {
            asm volatile("s_waitcnt vmcnt(4)" ::: "memory");
        } else {
            asm volatile("s_waitcnt vmcnt(0)" ::: "memory");
        }
        __builtin_amdgcn_s_barrier();        // all waves' slab-s writes complete
        asm volatile("" ::: "memory");       // fence: ds_reads may not hoist above barrier

        int slot = s & 3;
        bf16x8 bfr[4];
#pragma unroll
        for (int j = 0; j < 4; j++)
            bfr[j] = __builtin_bit_cast(bf16x8, SL[slot][1][quad * 256 + wn + j * 16 + lr]);
#pragma unroll
        for (int ih = 0; ih < 2; ih++) {
            bf16x8 af[4];
#pragma unroll
            for (int i = 0; i < 4; i++)
                af[i] = __builtin_bit_cast(bf16x8,
                    SL[slot][0][quad * 256 + wm + (ih * 4 + i) * 16 + lr]);
            __builtin_amdgcn_s_setprio(1);
#pragma unroll
            for (int i = 0; i < 4; i++)
#pragma unroll
                for (int j = 0; j < 4; j++)
                    acc[ih * 4 + i][j] = __builtin_amdgcn_mfma_f32_16x16x32_bf16(
                        af[i], bfr[j], acc[ih * 4 + i][j], 0, 0, 0);
            __builtin_amdgcn_s_setprio(0);
        }
    }

    float bc[4];
#pragma unroll
    for (int j = 0; j < 4; j++) bc[j] = bias[col0 + wn + j * 16 + lr];
#pragma unroll
    for (int i = 0; i < 8; i++) {
#pragma unroll
        for (int r = 0; r < 4; r++) {
            int R = (int)row0 + wm + i * 16 + quad * 4 + r;
#pragma unroll
            for (int j = 0; j < 4; j++) {
                int Cc = (int)col0 + wn + j * 16 + lr;
                float val = acc[i][j][r] + bc[j];
                if (mode == 0) {
                    int t3 = Cc >> 10, rem = Cc & 1023;
                    int head = rem >> 6, d = rem & 63;
                    int lb = R >> 8, nn = R & 255;
                    if (t3 == 0) val *= 0.125f;  // Dh^-0.5
                    ((bf16*)outp)[(size_t)t3 * qstride +
                                  ((size_t)((lb << 4) + head) * NTOK + nn) * DH + d] = (bf16)val;
                } else if (mode == 2) {
                    ((bf16*)outp)[(size_t)R * N + Cc] = (bf16)gelu_f(val);
                } else {
                    val += resid[(size_t)R * N + Cc];
                    ((float*)outp)[(size_t)R * N + Cc] = val;
                }
            }
        }
    }
}

// ------------- MFMA flash attention: one workgroup per (b,h), wave = 64 queries ------
// LDS (64 KB total): K half (128 keys x 64d, chunk-swizzled), V^T half (packed 2k/word,
// chunk-swizzled), per-wave P/Q scratch (64q x 64, chunk-swizzled).
__global__ __launch_bounds__(256, 2) void attn_mfma(
    const bf16* __restrict__ qkv, const float* __restrict__ biasq,
    bf16* __restrict__ outp, size_t qstride) {
    __shared__ u32x4 Ks4[1024];      // 16 KB
    __shared__ unsigned Vt32[4096];  // 16 KB
    __shared__ u32x4 PQ4[2048];      // 32 KB

    int bh = blockIdx.x, lb = bh >> 4, h = bh & 15;
    int tid = threadIdx.x, wave = tid >> 6, lane = tid & 63;
    int quad = lane >> 4, lr = lane & 15;
    int wq = wave << 6;
    const unsigned short* qg = (const unsigned short*)qkv + (size_t)bh * 16384;

    // ---- stage this wave's Q tile into its PQ region (wave-private), read A-frags ----
    u32x4* pqw = PQ4 + wave * 512;
#pragma unroll
    for (int it = 0; it < 8; it++) {
        int c = it * 64 + lane;
        int qrow = c >> 3, p = c & 7;
        pqw[qrow * 8 + (p ^ (qrow & 7))] =
            *(const u32x4*)(qg + (size_t)(wq + qrow) * 64 + p * 8);
    }
    bf16x8 qf[4][2];
#pragma unroll
    for (int i = 0; i < 4; i++)
#pragma unroll
        for (int ks = 0; ks < 2; ks++) {
            int qrow = i * 16 + lr;
            qf[i][ks] = __builtin_bit_cast(bf16x8,
                pqw[qrow * 8 + (((ks << 2) + quad) ^ (qrow & 7))]);
        }

    f32x4 o[4][4] = {};
    float mrun[4][4], lpart[4][4];
#pragma unroll
    for (int i = 0; i < 4; i++)
#pragma unroll
        for (int r = 0; r < 4; r++) { mrun[i][r] = -1e30f; lpart[i][r] = 0.f; }

    const float* bq = biasq + (size_t)h * 65536;  // [q][k]

    for (int half = 0; half < 2; half++) {
        __syncthreads();
        // stage K half (128 keys x 64 d), chunk-swizzled rows
        const unsigned short* kg = (const unsigned short*)qkv + qstride +
                                   (size_t)bh * 16384 + half * 8192;
#pragma unroll
        for (int it = 0; it < 4; it++) {
            int c = it * 256 + tid;
            int kr = c >> 3, p = c & 7;
            Ks4[kr * 8 + (p ^ (kr & 7))] = *(const u32x4*)(kg + (size_t)kr * 64 + p * 8);
        }
        // stage V^T half: Vt[d][k] packed 2 keys/word, chunk-swizzled
        const unsigned short* vg = (const unsigned short*)qkv + 2 * qstride +
                                   (size_t)bh * 16384 + half * 8192;
#pragma unroll
        for (int it = 0; it < 16; it++) {
            int idx = it * 256 + tid;
            int d = idx & 63, k2 = idx >> 6;  // k2: key pair 0..63
            unsigned lo = vg[(size_t)(2 * k2) * 64 + d];
            unsigned hi = vg[(size_t)(2 * k2 + 1) * 64 + d];
            int ck = k2 >> 2, w = k2 & 3;
            Vt32[d * 64 + ((ck ^ (d & 15)) << 2) + w] = lo | (hi << 16);
        }
        __syncthreads();

        for (int kb = 0; kb < 2; kb++) {
            // ---- S = Q K^T (64q x 64k) ----
            f32x4 s[4][4] = {};
#pragma unroll
            for (int ks = 0; ks < 2; ks++) {
                bf16x8 kf[4];
#pragma unroll
                for (int j = 0; j < 4; j++) {
                    int kr = kb * 64 + j * 16 + lr;
                    kf[j] = __builtin_bit_cast(bf16x8,
                        Ks4[kr * 8 + (((ks << 2) + quad) ^ (kr & 7))]);
                }
#pragma unroll
                for (int i = 0; i < 4; i++)
#pragma unroll
                    for (int j = 0; j < 4; j++)
                        s[i][j] = __builtin_amdgcn_mfma_f32_16x16x32_bf16(
                            qf[i][ks], kf[j], s[i][j], 0, 0, 0);
            }
            // ---- bias + online softmax (C-layout: row q = quad*4+r, col k = j*16+lr) ----
            int kglob = half * 128 + kb * 64;
#pragma unroll
            for (int i = 0; i < 4; i++) {
#pragma unroll
                for (int r = 0; r < 4; r++) {
                    int q = wq + i * 16 + quad * 4 + r;
                    const float* brow = bq + (size_t)q * 256 + kglob + lr;
                    float v0 = s[i][0][r] + brow[0];
                    float v1 = s[i][1][r] + brow[16];
                    float v2 = s[i][2][r] + brow[32];
                    float v3 = s[i][3][r] + brow[48];
                    float mx = fmaxf(fmaxf(v0, v1), fmaxf(v2, v3));
                    mx = fmaxf(mx, __shfl_xor(mx, 1));
                    mx = fmaxf(mx, __shfl_xor(mx, 2));
                    mx = fmaxf(mx, __shfl_xor(mx, 4));
                    mx = fmaxf(mx, __shfl_xor(mx, 8));
                    float mnew = fmaxf(mrun[i][r], mx);
                    float alpha = __expf(mrun[i][r] - mnew);
                    mrun[i][r] = mnew;
                    v0 = __expf(v0 - mnew);
                    v1 = __expf(v1 - mnew);
                    v2 = __expf(v2 - mnew);
                    v3 = __expf(v3 - mnew);
                    lpart[i][r] = lpart[i][r] * alpha + (v0 + v1 + v2 + v3);
                    s[i][0][r] = v0; s[i][1][r] = v1; s[i][2][r] = v2; s[i][3][r] = v3;
#pragma unroll
                    for (int dj = 0; dj < 4; dj++) o[i][dj][r] *= alpha;
                }
            }
            // ---- P -> wave-private LDS scratch in A-layout-friendly rows ----
            bf16* pqb = (bf16*)pqw;
#pragma unroll
            for (int i = 0; i < 4; i++)
#pragma unroll
                for (int r = 0; r < 4; r++) {
                    int ql = i * 16 + quad * 4 + r;
#pragma unroll
                    for (int j = 0; j < 4; j++) {
                        int col = j * 16 + lr;
                        int ck = col >> 3;
                        pqb[ql * 64 + ((ck ^ (ql & 7)) << 3) + (col & 7)] =
                            (bf16)s[i][j][r];
                    }
                }
            __syncthreads();  // orders mixed-width LDS writes before b128 reads
            // ---- O += P V ----
#pragma unroll
            for (int ks2 = 0; ks2 < 2; ks2++) {
                bf16x8 pf[4], vf[4];
#pragma unroll
                for (int i = 0; i < 4; i++) {
                    int ql = i * 16 + lr;
                    pf[i] = __builtin_bit_cast(bf16x8,
                        pqw[ql * 8 + (((ks2 << 2) + quad) ^ (ql & 7))]);
                }
#pragma unroll
                for (int dj = 0; dj < 4; dj++) {
                    int d = dj * 16 + lr;
                    int ck = kb * 8 + ks2 * 4 + quad;
                    vf[dj] = __builtin_bit_cast(bf16x8,
                        *(const u32x4*)(Vt32 + d * 64 + ((ck ^ (d & 15)) << 2)));
                }
#pragma unroll
                for (int i = 0; i < 4; i++)
#pragma unroll
                    for (int dj = 0; dj < 4; dj++)
                        o[i][dj] = __builtin_amdgcn_mfma_f32_16x16x32_bf16(
                            pf[i], vf[dj], o[i][dj], 0, 0, 0);
            }
        }
    }

    // ---- finalize: 1/l scale, store merged-heads bf16 ----
#pragma unroll
    for (int i = 0; i < 4; i++)
#pragma unroll
        for (int r = 0; r < 4; r++) {
            float lp = lpart[i][r];
            lp += __shfl_xor(lp, 1);
            lp += __shfl_xor(lp, 2);
            lp += __shfl_xor(lp, 4);
            lp += __shfl_xor(lp, 8);
            float inv = 1.0f / lp;
            int row = lb * 256 + wq + i * 16 + quad * 4 + r;
            bf16* orow = outp + (size_t)row * CDIM + h * DH;
#pragma unroll
            for (int dj = 0; dj < 4; dj++)
                orow[dj * 16 + lr] = (bf16)(o[i][dj][r] * inv);
        }
}

// ---------------- launch ----------------
extern "C" void kernel_launch(void* const* d_in, const int* in_sizes, int n_in,
                              void* d_out, int out_size, void* d_ws, size_t ws_size,
                              hipStream_t stream) {
    const float* x      = (const float*)d_in[0];
    const int*   rpi    = (const int*)d_in[1];
    const float* qkv_w  = (const float*)d_in[2];
    const float* qkv_b  = (const float*)d_in[3];
    const float* proj_w = (const float*)d_in[4];
    const float* proj_b = (const float*)d_in[5];
    const float* rpb    = (const float*)d_in[6];
    const float* ln1g   = (const float*)d_in[7];
    const float* ln1b   = (const float*)d_in[8];
    const float* ln2g   = (const float*)d_in[9];
    const float* ln2b   = (const float*)d_in[10];
    const float* fc1_w  = (const float*)d_in[11];
    const float* fc1_b  = (const float*)d_in[12];
    const float* fc2_w  = (const float*)d_in[13];
    const float* fc2_b  = (const float*)d_in[14];
    float* out = (float*)d_out;
    char* ws = (char*)d_ws;

    // --- fixed region: bf16 transposed weights + fp32 biasq (29,360,128 B) ---
    bf16* qkvT   = (bf16*)(ws);                 // 6,291,456
    bf16* projT  = (bf16*)(ws + 6291456ull);    // 2,097,152
    bf16* fc1T   = (bf16*)(ws + 8388608ull);    // 8,388,608
    bf16* fc2T   = (bf16*)(ws + 16777216ull);   // 8,388,608
    float* biasq = (float*)(ws + 25165824ull);  // 4,194,304
    const size_t fixed_end = 29360128ull;

    // --- adaptive chunk: per-row bytes = 2048 (hbuf) + 8192 (qkv or ff) ---
    long long avail = (long long)ws_size - (long long)fixed_end;
    long long rc = avail / 10240;
    rc &= ~255LL;
    if (rc < 256) rc = 256;
    if (rc > MROWS) rc = MROWS;
    const int Rc = (int)rc;
    bf16* hbuf   = (bf16*)(ws + fixed_end);                        // Rc*1024 bf16
    bf16* bigbuf = (bf16*)(ws + fixed_end + (size_t)Rc * 2048ull); // Rc*3072 or Rc*4096 bf16

    transpose_f32_bf16<<<dim3(3072 / 32, 1024 / 32), 256, 0, stream>>>(qkv_w, qkvT, 1024, 3072);
    transpose_f32_bf16<<<dim3(1024 / 32, 1024 / 32), 256, 0, stream>>>(proj_w, projT, 1024, 1024);
    transpose_f32_bf16<<<dim3(4096 / 32, 1024 / 32), 256, 0, stream>>>(fc1_w, fc1T, 1024, 4096);
    transpose_f32_bf16<<<dim3(1024 / 32, 4096 / 32), 256, 0, stream>>>(fc2_w, fc2T, 4096, 1024);
    biasq_kernel<<<4096, 256, 0, stream>>>(rpi, rpb, biasq);

    // --- phase A: LN1 -> qkv -> attention -> proj + residual ---
    for (int r0 = 0; r0 < MROWS; r0 += Rc) {
        int m = MROWS - r0 < Rc ? MROWS - r0 : Rc;
        size_t qs = (size_t)m * 1024;  // per-q/k/v stride in bf16 elems
        ln_kernel<<<m, 256, 0, stream>>>(x + (size_t)r0 * CDIM, ln1g, ln1b, hbuf);
        gemm_bt_kernel<<<dim3(3072 / 256, m / 256), 512, 0, stream>>>(
            hbuf, qkvT, qkv_b, nullptr, bigbuf, qs, m, 3072, 1024, 0);
        attn_mfma<<<(m / 256) * NH, 256, 0, stream>>>(bigbuf, biasq, hbuf, qs);
        gemm_bt_kernel<<<dim3(1024 / 256, m / 256), 512, 0, stream>>>(
            hbuf, projT, proj_b, x + (size_t)r0 * CDIM, out + (size_t)r0 * CDIM, 0,
            m, 1024, 1024, 3);
    }

    // --- phase B: LN2 -> fc1+gelu -> fc2 + residual ---
    for (int r0 = 0; r0 < MROWS; r0 += Rc) {
        int m = MROWS - r0 < Rc ? MROWS - r0 : Rc;
        ln_kernel<<<m, 256, 0, stream>>>(out + (size_t)r0 * CDIM, ln2g, ln2b, hbuf);
        gemm_bt_kernel<<<dim3(4096 / 256, m / 256), 512, 0, stream>>>(
            hbuf, fc1T, fc1_b, nullptr, bigbuf, 0, m, 4096, 1024, 2);
        gemm_bt_kernel<<<dim3(1024 / 256, m / 256), 512, 0, stream>>>(
            bigbuf, fc2T, fc2_b, out + (size_t)r0 * CDIM, out + (size_t)r0 * CDIM, 0,
            m, 1024, 4096, 3);
    }
}

// Round 4
// 1243.879 us; speedup vs baseline: 1.2639x; 1.0649x over previous
//
#include <hip/hip_runtime.h>
#include <hip/hip_bf16.h>
#include <math.h>

typedef __hip_bfloat16 bf16;
typedef __attribute__((ext_vector_type(8))) __bf16 bf16x8;
typedef __attribute__((ext_vector_type(4))) float f32x4;
typedef __attribute__((ext_vector_type(4))) unsigned u32x4;

#define NB 64
#define NTOK 256
#define CDIM 1024
#define NH 16
#define DH 64
#define DFF 4096
#define MROWS (NB * NTOK)  // 16384

// fast tanh-approx gelu in sigmoid form: one v_exp instead of a tanhf libcall chain
__device__ __forceinline__ float gelu_f(float x) {
    float t = 1.5957691216057308f * (x + 0.044715f * x * x * x);
    return x / (1.0f + __expf(-t));
}

// async 16B global->LDS (gfx950). LDS dest must be wave-uniform base; HW adds lane*16.
__device__ __forceinline__ void gload_lds16(const void* g, void* l) {
    __builtin_amdgcn_global_load_lds((const __attribute__((address_space(1))) void*)g,
                                     (__attribute__((address_space(3))) void*)l,
                                     16, 0, 0);
}

// ------------- transpose + downcast: in fp32 [R][C] -> out bf16 [C][R] -------------
__global__ void transpose_f32_bf16(const float* __restrict__ in, bf16* __restrict__ out,
                                   int R, int Cc) {
    __shared__ bf16 tile[32][33];
    int c0 = blockIdx.x * 32, r0 = blockIdx.y * 32;
    int t = threadIdx.x;
    int r = t >> 5, c = t & 31;
#pragma unroll
    for (int i = 0; i < 4; i++)
        tile[r + i * 8][c] = (bf16)in[(size_t)(r0 + r + i * 8) * Cc + c0 + c];
    __syncthreads();
#pragma unroll
    for (int i = 0; i < 4; i++)
        out[(size_t)(c0 + r + i * 8) * R + r0 + c] = tile[c][r + i * 8];
}

// ------------- layernorm: fp32 in -> bf16 out; one row (C=1024) per block -------------
__global__ __launch_bounds__(256) void ln_kernel(const float* __restrict__ xin,
                                                 const float* __restrict__ g,
                                                 const float* __restrict__ b,
                                                 bf16* __restrict__ outp) {
    __shared__ float red[8];
    int row = blockIdx.x, t = threadIdx.x;
    float4 v = ((const float4*)(xin + (size_t)row * CDIM))[t];
    float s = v.x + v.y + v.z + v.w;
    float q = v.x * v.x + v.y * v.y + v.z * v.z + v.w * v.w;
#pragma unroll
    for (int off = 32; off > 0; off >>= 1) {
        s += __shfl_down(s, off);
        q += __shfl_down(q, off);
    }
    int wave = t >> 6;
    if ((t & 63) == 0) { red[wave] = s; red[4 + wave] = q; }
    __syncthreads();
    float st = red[0] + red[1] + red[2] + red[3];
    float qt = red[4] + red[5] + red[6] + red[7];
    float mu = st * (1.0f / CDIM);
    float rstd = rsqrtf(qt * (1.0f / CDIM) - mu * mu + 1e-5f);
    float4 gv = ((const float4*)g)[t];
    float4 bv = ((const float4*)b)[t];
    bf16* orow = outp + (size_t)row * CDIM + t * 4;
    orow[0] = (bf16)((v.x - mu) * rstd * gv.x + bv.x);
    orow[1] = (bf16)((v.y - mu) * rstd * gv.y + bv.y);
    orow[2] = (bf16)((v.z - mu) * rstd * gv.z + bv.z);
    orow[3] = (bf16)((v.w - mu) * rstd * gv.w + bv.w);
}

// ------------- bias gather: biasq[h][q][k] = rpb[idx[q*256+k]*16+h] (fp32) -------------
__global__ void biasq_kernel(const int* __restrict__ idx, const float* __restrict__ rpb,
                             float* __restrict__ bq) {
    int e = blockIdx.x * 256 + threadIdx.x;
    int k = e & 255, q = (e >> 8) & 255, h = e >> 16;
    bq[e] = rpb[idx[q * 256 + k] * NH + h];
}

// ------------- GEMM: C[M,N] = A[M,K] @ Bt[N,K]^T  (A,Bt bf16; fp32 acc) -------------
// 256x256 tile, 8 waves, counted-vmcnt slab pipeline (T3+T4+T5) + T1 XCD swizzle:
//   K consumed in 32-wide slabs; 4 LDS slots x (A 16KB + B 16KB) = 128 KB.
//   iter s: issue slab s+2 (4 gload_lds) -> vmcnt(8) (slab s landed, s+1/s+2 STAY IN
//   FLIGHT across the barrier) -> s_barrier -> 32 MFMA under setprio(1).
// T1 (m204 bijective): round-robin XCD dispatch -> contiguous wg chunk per XCD, so the
// column-blocks sharing an A row-panel hit the SAME XCD L2 (A fetched once per XCD).
// mode 0: +bias, q*=0.125 -> scatter to bf16 qkv buffer [3][Bc][H][N][DH] (stride qstride)
// mode 2: +bias, gelu -> bf16 row-major
// mode 3: +bias, +fp32 resid -> fp32 row-major (outp may alias resid; same-thread RMW)
__global__ __launch_bounds__(512, 2) void gemm_bt_kernel(
    const bf16* __restrict__ Abf, const bf16* __restrict__ Btbf,
    const float* __restrict__ bias, const float* resid,
    void* outp, size_t qstride, int M, int N, int K, int mode) {
    __shared__ __align__(16) u32x4 SL[4][2][1024];  // 4 slots x (A,B) x 16KB = 128 KB
    const unsigned short* A = (const unsigned short*)Abf;
    const unsigned short* Bt = (const unsigned short*)Btbf;
    int tid = threadIdx.x;
    int wave = tid >> 6, lane = tid & 63;
    int quad = lane >> 4, lr = lane & 15;
    int wm = (wave >> 2) << 7;  // 0 / 128
    int wn = (wave & 3) << 6;   // 0 / 64 / 128 / 192

    // T1: XCD-aware bijective block swizzle (m204)
    unsigned nx = gridDim.x;
    unsigned nwg = nx * gridDim.y;
    unsigned orig = blockIdx.y * nx + blockIdx.x;
    unsigned q8 = nwg >> 3, r8 = nwg & 7u;
    unsigned xcd = orig & 7u, io = orig >> 3;
    unsigned wg = (xcd < r8 ? xcd * (q8 + 1u) : r8 * (q8 + 1u) + (xcd - r8) * q8) + io;
    size_t row0 = (size_t)(wg / nx) << 8;
    size_t col0 = (size_t)(wg % nx) << 8;

    const unsigned short* Ag = A + row0 * K;
    const unsigned short* Bg = Bt + col0 * K;
    f32x4 acc[8][4] = {};

    const int wbase = tid & ~63;  // wave-uniform LDS slot base

    // stage slab s (k in [s*32, s*32+32)): A half + B half, 4 gload_lds / thread
    auto stage = [&](int s) {
        int slot = s & 3;
        int kbase = s << 5;
#pragma unroll
        for (int it = 0; it < 2; it++) {
            int ch = it * 512 + tid;
            int kk = ch >> 8, r = ch & 255;
            gload_lds16(Ag + (size_t)r * K + (kbase + kk * 8),
                        (void*)&SL[slot][0][it * 512 + wbase]);
        }
#pragma unroll
        for (int it = 0; it < 2; it++) {
            int ch = it * 512 + tid;
            int kk = ch >> 8, r = ch & 255;
            gload_lds16(Bg + (size_t)r * K + (kbase + kk * 8),
                        (void*)&SL[slot][1][it * 512 + wbase]);
        }
    };

    int S = K >> 5;  // #slabs (>= 32 for all our shapes)
    stage(0);
    stage(1);
    for (int s = 0; s < S; s++) {
        if (s + 2 < S) {
            stage(s + 2);
            asm volatile("s_waitcnt vmcnt(8)" ::: "memory");  // slab s landed; 8 in flight
        } else if (s + 1 < S) {
            asm volatile("s_waitcnt vmcnt(4)" ::: "memory");
        } else {
            asm volatile("s_waitcnt vmcnt(0)" ::: "memory");
        }
        __builtin_amdgcn_s_barrier();        // all waves' slab-s writes complete
        asm volatile("" ::: "memory");       // fence: ds_reads may not hoist above barrier

        int slot = s & 3;
        bf16x8 bfr[4];
#pragma unroll
        for (int j = 0; j < 4; j++)
            bfr[j] = __builtin_bit_cast(bf16x8, SL[slot][1][quad * 256 + wn + j * 16 + lr]);
#pragma unroll
        for (int ih = 0; ih < 2; ih++) {
            bf16x8 af[4];
#pragma unroll
            for (int i = 0; i < 4; i++)
                af[i] = __builtin_bit_cast(bf16x8,
                    SL[slot][0][quad * 256 + wm + (ih * 4 + i) * 16 + lr]);
            __builtin_amdgcn_s_setprio(1);
#pragma unroll
            for (int i = 0; i < 4; i++)
#pragma unroll
                for (int j = 0; j < 4; j++)
                    acc[ih * 4 + i][j] = __builtin_amdgcn_mfma_f32_16x16x32_bf16(
                        af[i], bfr[j], acc[ih * 4 + i][j], 0, 0, 0);
            __builtin_amdgcn_s_setprio(0);
        }
    }

    float bc[4];
#pragma unroll
    for (int j = 0; j < 4; j++) bc[j] = bias[col0 + wn + j * 16 + lr];
#pragma unroll
    for (int i = 0; i < 8; i++) {
#pragma unroll
        for (int r = 0; r < 4; r++) {
            int R = (int)row0 + wm + i * 16 + quad * 4 + r;
#pragma unroll
            for (int j = 0; j < 4; j++) {
                int Cc = (int)col0 + wn + j * 16 + lr;
                float val = acc[i][j][r] + bc[j];
                if (mode == 0) {
                    int t3 = Cc >> 10, rem = Cc & 1023;
                    int head = rem >> 6, d = rem & 63;
                    int lb = R >> 8, nn = R & 255;
                    if (t3 == 0) val *= 0.125f;  // Dh^-0.5
                    ((bf16*)outp)[(size_t)t3 * qstride +
                                  ((size_t)((lb << 4) + head) * NTOK + nn) * DH + d] = (bf16)val;
                } else if (mode == 2) {
                    ((bf16*)outp)[(size_t)R * N + Cc] = (bf16)gelu_f(val);
                } else {
                    val += resid[(size_t)R * N + Cc];
                    ((float*)outp)[(size_t)R * N + Cc] = val;
                }
            }
        }
    }
}

// ------------- MFMA flash attention: one workgroup per (b,h), wave = 64 queries ------
// LDS (64 KB total): K half (128 keys x 64d, chunk-swizzled), V^T half (packed 2k/word,
// chunk-swizzled), per-wave P/Q scratch (64q x 64, chunk-swizzled).
__global__ __launch_bounds__(256, 2) void attn_mfma(
    const bf16* __restrict__ qkv, const float* __restrict__ biasq,
    bf16* __restrict__ outp, size_t qstride) {
    __shared__ u32x4 Ks4[1024];      // 16 KB
    __shared__ unsigned Vt32[4096];  // 16 KB
    __shared__ u32x4 PQ4[2048];      // 32 KB

    int bh = blockIdx.x, lb = bh >> 4, h = bh & 15;
    int tid = threadIdx.x, wave = tid >> 6, lane = tid & 63;
    int quad = lane >> 4, lr = lane & 15;
    int wq = wave << 6;
    const unsigned short* qg = (const unsigned short*)qkv + (size_t)bh * 16384;

    // ---- stage this wave's Q tile into its PQ region (wave-private), read A-frags ----
    u32x4* pqw = PQ4 + wave * 512;
#pragma unroll
    for (int it = 0; it < 8; it++) {
        int c = it * 64 + lane;
        int qrow = c >> 3, p = c & 7;
        pqw[qrow * 8 + (p ^ (qrow & 7))] =
            *(const u32x4*)(qg + (size_t)(wq + qrow) * 64 + p * 8);
    }
    bf16x8 qf[4][2];
#pragma unroll
    for (int i = 0; i < 4; i++)
#pragma unroll
        for (int ks = 0; ks < 2; ks++) {
            int qrow = i * 16 + lr;
            qf[i][ks] = __builtin_bit_cast(bf16x8,
                pqw[qrow * 8 + (((ks << 2) + quad) ^ (qrow & 7))]);
        }

    f32x4 o[4][4] = {};
    float mrun[4][4], lpart[4][4];
#pragma unroll
    for (int i = 0; i < 4; i++)
#pragma unroll
        for (int r = 0; r < 4; r++) { mrun[i][r] = -1e30f; lpart[i][r] = 0.f; }

    const float* bq = biasq + (size_t)h * 65536;  // [q][k]

    for (int half = 0; half < 2; half++) {
        __syncthreads();
        // stage K half (128 keys x 64 d), chunk-swizzled rows
        const unsigned short* kg = (const unsigned short*)qkv + qstride +
                                   (size_t)bh * 16384 + half * 8192;
#pragma unroll
        for (int it = 0; it < 4; it++) {
            int c = it * 256 + tid;
            int kr = c >> 3, p = c & 7;
            Ks4[kr * 8 + (p ^ (kr & 7))] = *(const u32x4*)(kg + (size_t)kr * 64 + p * 8);
        }
        // stage V^T half: Vt[d][k] packed 2 keys/word, chunk-swizzled
        const unsigned short* vg = (const unsigned short*)qkv + 2 * qstride +
                                   (size_t)bh * 16384 + half * 8192;
#pragma unroll
        for (int it = 0; it < 16; it++) {
            int idx = it * 256 + tid;
            int d = idx & 63, k2 = idx >> 6;  // k2: key pair 0..63
            unsigned lo = vg[(size_t)(2 * k2) * 64 + d];
            unsigned hi = vg[(size_t)(2 * k2 + 1) * 64 + d];
            int ck = k2 >> 2, w = k2 & 3;
            Vt32[d * 64 + ((ck ^ (d & 15)) << 2) + w] = lo | (hi << 16);
        }
        __syncthreads();

        for (int kb = 0; kb < 2; kb++) {
            // ---- S = Q K^T (64q x 64k) ----
            f32x4 s[4][4] = {};
#pragma unroll
            for (int ks = 0; ks < 2; ks++) {
                bf16x8 kf[4];
#pragma unroll
                for (int j = 0; j < 4; j++) {
                    int kr = kb * 64 + j * 16 + lr;
                    kf[j] = __builtin_bit_cast(bf16x8,
                        Ks4[kr * 8 + (((ks << 2) + quad) ^ (kr & 7))]);
                }
#pragma unroll
                for (int i = 0; i < 4; i++)
#pragma unroll
                    for (int j = 0; j < 4; j++)
                        s[i][j] = __builtin_amdgcn_mfma_f32_16x16x32_bf16(
                            qf[i][ks], kf[j], s[i][j], 0, 0, 0);
            }
            // ---- bias + online softmax (C-layout: row q = quad*4+r, col k = j*16+lr) ----
            int kglob = half * 128 + kb * 64;
#pragma unroll
            for (int i = 0; i < 4; i++) {
#pragma unroll
                for (int r = 0; r < 4; r++) {
                    int q = wq + i * 16 + quad * 4 + r;
                    const float* brow = bq + (size_t)q * 256 + kglob + lr;
                    float v0 = s[i][0][r] + brow[0];
                    float v1 = s[i][1][r] + brow[16];
                    float v2 = s[i][2][r] + brow[32];
                    float v3 = s[i][3][r] + brow[48];
                    float mx = fmaxf(fmaxf(v0, v1), fmaxf(v2, v3));
                    mx = fmaxf(mx, __shfl_xor(mx, 1));
                    mx = fmaxf(mx, __shfl_xor(mx, 2));
                    mx = fmaxf(mx, __shfl_xor(mx, 4));
                    mx = fmaxf(mx, __shfl_xor(mx, 8));
                    float mnew = fmaxf(mrun[i][r], mx);
                    float alpha = __expf(mrun[i][r] - mnew);
                    mrun[i][r] = mnew;
                    v0 = __expf(v0 - mnew);
                    v1 = __expf(v1 - mnew);
                    v2 = __expf(v2 - mnew);
                    v3 = __expf(v3 - mnew);
                    lpart[i][r] = lpart[i][r] * alpha + (v0 + v1 + v2 + v3);
                    s[i][0][r] = v0; s[i][1][r] = v1; s[i][2][r] = v2; s[i][3][r] = v3;
#pragma unroll
                    for (int dj = 0; dj < 4; dj++) o[i][dj][r] *= alpha;
                }
            }
            // ---- P -> wave-private LDS scratch in A-layout-friendly rows ----
            bf16* pqb = (bf16*)pqw;
#pragma unroll
            for (int i = 0; i < 4; i++)
#pragma unroll
                for (int r = 0; r < 4; r++) {
                    int ql = i * 16 + quad * 4 + r;
#pragma unroll
                    for (int j = 0; j < 4; j++) {
                        int col = j * 16 + lr;
                        int ck = col >> 3;
                        pqb[ql * 64 + ((ck ^ (ql & 7)) << 3) + (col & 7)] =
                            (bf16)s[i][j][r];
                    }
                }
            __syncthreads();  // orders mixed-width LDS writes before b128 reads
            // ---- O += P V ----
#pragma unroll
            for (int ks2 = 0; ks2 < 2; ks2++) {
                bf16x8 pf[4], vf[4];
#pragma unroll
                for (int i = 0; i < 4; i++) {
                    int ql = i * 16 + lr;
                    pf[i] = __builtin_bit_cast(bf16x8,
                        pqw[ql * 8 + (((ks2 << 2) + quad) ^ (ql & 7))]);
                }
#pragma unroll
                for (int dj = 0; dj < 4; dj++) {
                    int d = dj * 16 + lr;
                    int ck = kb * 8 + ks2 * 4 + quad;
                    vf[dj] = __builtin_bit_cast(bf16x8,
                        *(const u32x4*)(Vt32 + d * 64 + ((ck ^ (d & 15)) << 2)));
                }
#pragma unroll
                for (int i = 0; i < 4; i++)
#pragma unroll
                    for (int dj = 0; dj < 4; dj++)
                        o[i][dj] = __builtin_amdgcn_mfma_f32_16x16x32_bf16(
                            pf[i], vf[dj], o[i][dj], 0, 0, 0);
            }
        }
    }

    // ---- finalize: 1/l scale, store merged-heads bf16 ----
#pragma unroll
    for (int i = 0; i < 4; i++)
#pragma unroll
        for (int r = 0; r < 4; r++) {
            float lp = lpart[i][r];
            lp += __shfl_xor(lp, 1);
            lp += __shfl_xor(lp, 2);
            lp += __shfl_xor(lp, 4);
            lp += __shfl_xor(lp, 8);
            float inv = 1.0f / lp;
            int row = lb * 256 + wq + i * 16 + quad * 4 + r;
            bf16* orow = outp + (size_t)row * CDIM + h * DH;
#pragma unroll
            for (int dj = 0; dj < 4; dj++)
                orow[dj * 16 + lr] = (bf16)(o[i][dj][r] * inv);
        }
}

// ---------------- launch ----------------
extern "C" void kernel_launch(void* const* d_in, const int* in_sizes, int n_in,
                              void* d_out, int out_size, void* d_ws, size_t ws_size,
                              hipStream_t stream) {
    const float* x      = (const float*)d_in[0];
    const int*   rpi    = (const int*)d_in[1];
    const float* qkv_w  = (const float*)d_in[2];
    const float* qkv_b  = (const float*)d_in[3];
    const float* proj_w = (const float*)d_in[4];
    const float* proj_b = (const float*)d_in[5];
    const float* rpb    = (const float*)d_in[6];
    const float* ln1g   = (const float*)d_in[7];
    const float* ln1b   = (const float*)d_in[8];
    const float* ln2g   = (const float*)d_in[9];
    const float* ln2b   = (const float*)d_in[10];
    const float* fc1_w  = (const float*)d_in[11];
    const float* fc1_b  = (const float*)d_in[12];
    const float* fc2_w  = (const float*)d_in[13];
    const float* fc2_b  = (const float*)d_in[14];
    float* out = (float*)d_out;
    char* ws = (char*)d_ws;

    // --- fixed region: bf16 transposed weights + fp32 biasq (29,360,128 B) ---
    bf16* qkvT   = (bf16*)(ws);                 // 6,291,456
    bf16* projT  = (bf16*)(ws + 6291456ull);    // 2,097,152
    bf16* fc1T   = (bf16*)(ws + 8388608ull);    // 8,388,608
    bf16* fc2T   = (bf16*)(ws + 16777216ull);   // 8,388,608
    float* biasq = (float*)(ws + 25165824ull);  // 4,194,304
    const size_t fixed_end = 29360128ull;

    // --- adaptive chunk: per-row bytes = 2048 (hbuf) + 8192 (qkv or ff) ---
    long long avail = (long long)ws_size - (long long)fixed_end;
    long long rc = avail / 10240;
    rc &= ~255LL;
    if (rc < 256) rc = 256;
    if (rc > MROWS) rc = MROWS;
    const int Rc = (int)rc;
    bf16* hbuf   = (bf16*)(ws + fixed_end);                        // Rc*1024 bf16
    bf16* bigbuf = (bf16*)(ws + fixed_end + (size_t)Rc * 2048ull); // Rc*3072 or Rc*4096 bf16

    transpose_f32_bf16<<<dim3(3072 / 32, 1024 / 32), 256, 0, stream>>>(qkv_w, qkvT, 1024, 3072);
    transpose_f32_bf16<<<dim3(1024 / 32, 1024 / 32), 256, 0, stream>>>(proj_w, projT, 1024, 1024);
    transpose_f32_bf16<<<dim3(4096 / 32, 1024 / 32), 256, 0, stream>>>(fc1_w, fc1T, 1024, 4096);
    transpose_f32_bf16<<<dim3(1024 / 32, 4096 / 32), 256, 0, stream>>>(fc2_w, fc2T, 4096, 1024);
    biasq_kernel<<<4096, 256, 0, stream>>>(rpi, rpb, biasq);

    // --- phase A: LN1 -> qkv -> attention -> proj + residual ---
    for (int r0 = 0; r0 < MROWS; r0 += Rc) {
        int m = MROWS - r0 < Rc ? MROWS - r0 : Rc;
        size_t qs = (size_t)m * 1024;  // per-q/k/v stride in bf16 elems
        ln_kernel<<<m, 256, 0, stream>>>(x + (size_t)r0 * CDIM, ln1g, ln1b, hbuf);
        gemm_bt_kernel<<<dim3(3072 / 256, m / 256), 512, 0, stream>>>(
            hbuf, qkvT, qkv_b, nullptr, bigbuf, qs, m, 3072, 1024, 0);
        attn_mfma<<<(m / 256) * NH, 256, 0, stream>>>(bigbuf, biasq, hbuf, qs);
        gemm_bt_kernel<<<dim3(1024 / 256, m / 256), 512, 0, stream>>>(
            hbuf, projT, proj_b, x + (size_t)r0 * CDIM, out + (size_t)r0 * CDIM, 0,
            m, 1024, 1024, 3);
    }

    // --- phase B: LN2 -> fc1+gelu -> fc2 + residual ---
    for (int r0 = 0; r0 < MROWS; r0 += Rc) {
        int m = MROWS - r0 < Rc ? MROWS - r0 : Rc;
        ln_kernel<<<m, 256, 0, stream>>>(out + (size_t)r0 * CDIM, ln2g, ln2b, hbuf);
        gemm_bt_kernel<<<dim3(4096 / 256, m / 256), 512, 0, stream>>>(
            hbuf, fc1T, fc1_b, nullptr, bigbuf, 0, m, 4096, 1024, 2);
        gemm_bt_kernel<<<dim3(1024 / 256, m / 256), 512, 0, stream>>>(
            bigbuf, fc2T, fc2_b, out + (size_t)r0 * CDIM, out + (size_t)r0 * CDIM, 0,
            m, 1024, 4096, 3);
    }
}

// Round 5
// 1218.974 us; speedup vs baseline: 1.2897x; 1.0204x over previous
//
#include <hip/hip_runtime.h>
#include <hip/hip_bf16.h>
#include <math.h>

typedef __hip_bfloat16 bf16;
typedef __attribute__((ext_vector_type(8))) __bf16 bf16x8;
typedef __attribute__((ext_vector_type(4))) float f32x4;
typedef __attribute__((ext_vector_type(4))) unsigned u32x4;

#define NB 64
#define NTOK 256
#define CDIM 1024
#define NH 16
#define DH 64
#define DFF 4096
#define MROWS (NB * NTOK)  // 16384

// fast tanh-approx gelu in sigmoid form: one v_exp instead of a tanhf libcall chain
__device__ __forceinline__ float gelu_f(float x) {
    float t = 1.5957691216057308f * (x + 0.044715f * x * x * x);
    return x / (1.0f + __expf(-t));
}

// async 16B global->LDS (gfx950). LDS dest must be wave-uniform base; HW adds lane*16.
__device__ __forceinline__ void gload_lds16(const void* g, void* l) {
    __builtin_amdgcn_global_load_lds((const __attribute__((address_space(1))) void*)g,
                                     (__attribute__((address_space(3))) void*)l,
                                     16, 0, 0);
}

// ------------- transpose + downcast: in fp32 [R][C] -> out bf16 [C][R] -------------
__global__ void transpose_f32_bf16(const float* __restrict__ in, bf16* __restrict__ out,
                                   int R, int Cc) {
    __shared__ bf16 tile[32][33];
    int c0 = blockIdx.x * 32, r0 = blockIdx.y * 32;
    int t = threadIdx.x;
    int r = t >> 5, c = t & 31;
#pragma unroll
    for (int i = 0; i < 4; i++)
        tile[r + i * 8][c] = (bf16)in[(size_t)(r0 + r + i * 8) * Cc + c0 + c];
    __syncthreads();
#pragma unroll
    for (int i = 0; i < 4; i++)
        out[(size_t)(c0 + r + i * 8) * R + r0 + c] = tile[c][r + i * 8];
}

// ------------- layernorm: fp32 in -> bf16 out; one row (C=1024) per block -------------
__global__ __launch_bounds__(256) void ln_kernel(const float* __restrict__ xin,
                                                 const float* __restrict__ g,
                                                 const float* __restrict__ b,
                                                 bf16* __restrict__ outp) {
    __shared__ float red[8];
    int row = blockIdx.x, t = threadIdx.x;
    float4 v = ((const float4*)(xin + (size_t)row * CDIM))[t];
    float s = v.x + v.y + v.z + v.w;
    float q = v.x * v.x + v.y * v.y + v.z * v.z + v.w * v.w;
#pragma unroll
    for (int off = 32; off > 0; off >>= 1) {
        s += __shfl_down(s, off);
        q += __shfl_down(q, off);
    }
    int wave = t >> 6;
    if ((t & 63) == 0) { red[wave] = s; red[4 + wave] = q; }
    __syncthreads();
    float st = red[0] + red[1] + red[2] + red[3];
    float qt = red[4] + red[5] + red[6] + red[7];
    float mu = st * (1.0f / CDIM);
    float rstd = rsqrtf(qt * (1.0f / CDIM) - mu * mu + 1e-5f);
    float4 gv = ((const float4*)g)[t];
    float4 bv = ((const float4*)b)[t];
    bf16* orow = outp + (size_t)row * CDIM + t * 4;
    orow[0] = (bf16)((v.x - mu) * rstd * gv.x + bv.x);
    orow[1] = (bf16)((v.y - mu) * rstd * gv.y + bv.y);
    orow[2] = (bf16)((v.z - mu) * rstd * gv.z + bv.z);
    orow[3] = (bf16)((v.w - mu) * rstd * gv.w + bv.w);
}

// ------------- bias gather, permuted for float4 softmax loads (fp32) -------------
// layout: bq[h][q][ck][lr][j] = rpb[idx[q*256 + (ck*64 + j*16 + lr)]*16 + h]
// so a softmax step for row q, k-chunk ck reads ONE float4 at (q*256 + ck*64 + lr*4).
__global__ void biasq_kernel(const int* __restrict__ idx, const float* __restrict__ rpb,
                             float* __restrict__ bq) {
    int e = blockIdx.x * 256 + threadIdx.x;  // 1,048,576 total
    int j = e & 3, lr = (e >> 2) & 15, ck = (e >> 6) & 3, q = (e >> 8) & 255, h = e >> 16;
    int k = ck * 64 + j * 16 + lr;
    bq[e] = rpb[idx[q * 256 + k] * NH + h];
}

// ------------- GEMM: C[M,N] = A[M,K] @ Bt[N,K]^T  (A,Bt bf16; fp32 acc) -------------
// 256x256 tile, 8 waves, counted-vmcnt slab pipeline (T3+T4+T5) + T1 XCD swizzle:
//   K consumed in 32-wide slabs; 4 LDS slots x (A 16KB + B 16KB) = 128 KB.
//   iter s: issue slab s+2 (4 gload_lds) -> vmcnt(8) (slab s landed, s+1/s+2 STAY IN
//   FLIGHT across the barrier) -> s_barrier -> 32 MFMA under setprio(1).
// T1 (m204 bijective): contiguous wg chunk per XCD -> shared panels hit the same L2.
// mode 0: +bias, scale cols<1024 by 0.125 -> bf16 row-major [M][3072] (coalesced)
// mode 2: +bias, gelu -> bf16 row-major
// mode 3: +bias, +fp32 resid -> fp32 row-major (outp may alias resid; same-thread RMW)
__global__ __launch_bounds__(512, 2) void gemm_bt_kernel(
    const bf16* __restrict__ Abf, const bf16* __restrict__ Btbf,
    const float* __restrict__ bias, const float* resid,
    void* outp, size_t qstride, int M, int N, int K, int mode) {
    __shared__ __align__(16) u32x4 SL[4][2][1024];  // 4 slots x (A,B) x 16KB = 128 KB
    const unsigned short* A = (const unsigned short*)Abf;
    const unsigned short* Bt = (const unsigned short*)Btbf;
    int tid = threadIdx.x;
    int wave = tid >> 6, lane = tid & 63;
    int quad = lane >> 4, lr = lane & 15;
    int wm = (wave >> 2) << 7;  // 0 / 128
    int wn = (wave & 3) << 6;   // 0 / 64 / 128 / 192

    // T1: XCD-aware bijective block swizzle (m204)
    unsigned nx = gridDim.x;
    unsigned nwg = nx * gridDim.y;
    unsigned orig = blockIdx.y * nx + blockIdx.x;
    unsigned q8 = nwg >> 3, r8 = nwg & 7u;
    unsigned xcd = orig & 7u, io = orig >> 3;
    unsigned wg = (xcd < r8 ? xcd * (q8 + 1u) : r8 * (q8 + 1u) + (xcd - r8) * q8) + io;
    size_t row0 = (size_t)(wg / nx) << 8;
    size_t col0 = (size_t)(wg % nx) << 8;

    const unsigned short* Ag = A + row0 * K;
    const unsigned short* Bg = Bt + col0 * K;
    f32x4 acc[8][4] = {};

    const int wbase = tid & ~63;  // wave-uniform LDS slot base

    // stage slab s (k in [s*32, s*32+32)): A half + B half, 4 gload_lds / thread
    auto stage = [&](int s) {
        int slot = s & 3;
        int kbase = s << 5;
#pragma unroll
        for (int it = 0; it < 2; it++) {
            int ch = it * 512 + tid;
            int kk = ch >> 8, r = ch & 255;
            gload_lds16(Ag + (size_t)r * K + (kbase + kk * 8),
                        (void*)&SL[slot][0][it * 512 + wbase]);
        }
#pragma unroll
        for (int it = 0; it < 2; it++) {
            int ch = it * 512 + tid;
            int kk = ch >> 8, r = ch & 255;
            gload_lds16(Bg + (size_t)r * K + (kbase + kk * 8),
                        (void*)&SL[slot][1][it * 512 + wbase]);
        }
    };

    int S = K >> 5;  // #slabs (>= 32 for all our shapes)
    stage(0);
    stage(1);
    for (int s = 0; s < S; s++) {
        if (s + 2 < S) {
            stage(s + 2);
            asm volatile("s_waitcnt vmcnt(8)" ::: "memory");  // slab s landed; 8 in flight
        } else if (s + 1 < S) {
            asm volatile("s_waitcnt vmcnt(4)" ::: "memory");
        } else {
            asm volatile("s_waitcnt vmcnt(0)" ::: "memory");
        }
        __builtin_amdgcn_s_barrier();        // all waves' slab-s writes complete
        asm volatile("" ::: "memory");       // fence: ds_reads may not hoist above barrier

        int slot = s & 3;
        bf16x8 bfr[4];
#pragma unroll
        for (int j = 0; j < 4; j++)
            bfr[j] = __builtin_bit_cast(bf16x8, SL[slot][1][quad * 256 + wn + j * 16 + lr]);
#pragma unroll
        for (int ih = 0; ih < 2; ih++) {
            bf16x8 af[4];
#pragma unroll
            for (int i = 0; i < 4; i++)
                af[i] = __builtin_bit_cast(bf16x8,
                    SL[slot][0][quad * 256 + wm + (ih * 4 + i) * 16 + lr]);
            __builtin_amdgcn_s_setprio(1);
#pragma unroll
            for (int i = 0; i < 4; i++)
#pragma unroll
                for (int j = 0; j < 4; j++)
                    acc[ih * 4 + i][j] = __builtin_amdgcn_mfma_f32_16x16x32_bf16(
                        af[i], bfr[j], acc[ih * 4 + i][j], 0, 0, 0);
            __builtin_amdgcn_s_setprio(0);
        }
    }

    float bc[4];
#pragma unroll
    for (int j = 0; j < 4; j++) bc[j] = bias[col0 + wn + j * 16 + lr];
#pragma unroll
    for (int i = 0; i < 8; i++) {
#pragma unroll
        for (int r = 0; r < 4; r++) {
            int R = (int)row0 + wm + i * 16 + quad * 4 + r;
#pragma unroll
            for (int j = 0; j < 4; j++) {
                int Cc = (int)col0 + wn + j * 16 + lr;
                float val = acc[i][j][r] + bc[j];
                if (mode == 0) {
                    if (Cc < 1024) val *= 0.125f;  // Dh^-0.5 on q columns
                    ((bf16*)outp)[(size_t)R * N + Cc] = (bf16)val;
                } else if (mode == 2) {
                    ((bf16*)outp)[(size_t)R * N + Cc] = (bf16)gelu_f(val);
                } else {
                    val += resid[(size_t)R * N + Cc];
                    ((float*)outp)[(size_t)R * N + Cc] = val;
                }
            }
        }
    }
}

// ------------- MFMA flash attention: one workgroup per (b,h), wave = 64 queries ------
// qkv input is row-major [M][3072] (q|k|v each 1024 cols, head h at col h*64).
// LDS (64 KB): K half (128 keys x 64d, chunk-swizzled), V^T half (packed 2k/word,
// chunk-swizzled), per-wave P/Q/O scratch (wave-private; NO block barrier needed).
__global__ __launch_bounds__(256, 2) void attn_mfma(
    const bf16* __restrict__ qkv, const float* __restrict__ biasq,
    bf16* __restrict__ outp, size_t qstride) {
    __shared__ u32x4 Ks4[1024];      // 16 KB
    __shared__ unsigned Vt32[4096];  // 16 KB
    __shared__ u32x4 PQ4[2048];      // 32 KB

    int bh = blockIdx.x, lb = bh >> 4, h = bh & 15;
    int tid = threadIdx.x, wave = tid >> 6, lane = tid & 63;
    int quad = lane >> 4, lr = lane & 15;
    int wq = wave << 6;
    int tok0 = lb << 8;
    const unsigned short* base = (const unsigned short*)qkv;
    const unsigned short* qg = base + (size_t)tok0 * 3072 + h * DH;

    // ---- stage this wave's Q tile into its PQ region (wave-private), read A-frags ----
    u32x4* pqw = PQ4 + wave * 512;
#pragma unroll
    for (int it = 0; it < 8; it++) {
        int c = it * 64 + lane;
        int qrow = c >> 3, p = c & 7;
        pqw[qrow * 8 + (p ^ (qrow & 7))] =
            *(const u32x4*)(qg + (size_t)(wq + qrow) * 3072 + p * 8);
    }
    bf16x8 qf[4][2];
#pragma unroll
    for (int i = 0; i < 4; i++)
#pragma unroll
        for (int ks = 0; ks < 2; ks++) {
            int qrow = i * 16 + lr;
            qf[i][ks] = __builtin_bit_cast(bf16x8,
                pqw[qrow * 8 + (((ks << 2) + quad) ^ (qrow & 7))]);
        }

    f32x4 o[4][4] = {};
    float mrun[4][4], lpart[4][4];
#pragma unroll
    for (int i = 0; i < 4; i++)
#pragma unroll
        for (int r = 0; r < 4; r++) { mrun[i][r] = -1e30f; lpart[i][r] = 0.f; }

    const float* bq = biasq + (size_t)h * 65536;  // [q][ck][lr][j] fp32

    for (int half = 0; half < 2; half++) {
        __syncthreads();  // protect shared K/V LDS from overwrite while still in use
        // stage K half (128 keys x 64 d), chunk-swizzled rows
        const unsigned short* kg = base + (size_t)(tok0 + half * 128) * 3072 + CDIM + h * DH;
#pragma unroll
        for (int it = 0; it < 4; it++) {
            int c = it * 256 + tid;
            int kr = c >> 3, p = c & 7;
            Ks4[kr * 8 + (p ^ (kr & 7))] = *(const u32x4*)(kg + (size_t)kr * 3072 + p * 8);
        }
        // stage V^T half: Vt[d][k] packed 2 keys/word, chunk-swizzled
        const unsigned short* vg = base + (size_t)(tok0 + half * 128) * 3072 + 2 * CDIM + h * DH;
#pragma unroll
        for (int it = 0; it < 16; it++) {
            int idx = it * 256 + tid;
            int d = idx & 63, k2 = idx >> 6;  // k2: key pair 0..63
            unsigned lo = vg[(size_t)(2 * k2) * 3072 + d];
            unsigned hi = vg[(size_t)(2 * k2 + 1) * 3072 + d];
            int ck = k2 >> 2, w = k2 & 3;
            Vt32[d * 64 + ((ck ^ (d & 15)) << 2) + w] = lo | (hi << 16);
        }
        __syncthreads();

        for (int kb = 0; kb < 2; kb++) {
            // ---- S = Q K^T (64q x 64k) ----
            f32x4 s[4][4] = {};
#pragma unroll
            for (int ks = 0; ks < 2; ks++) {
                bf16x8 kf[4];
#pragma unroll
                for (int j = 0; j < 4; j++) {
                    int kr = kb * 64 + j * 16 + lr;
                    kf[j] = __builtin_bit_cast(bf16x8,
                        Ks4[kr * 8 + (((ks << 2) + quad) ^ (kr & 7))]);
                }
#pragma unroll
                for (int i = 0; i < 4; i++)
#pragma unroll
                    for (int j = 0; j < 4; j++)
                        s[i][j] = __builtin_amdgcn_mfma_f32_16x16x32_bf16(
                            qf[i][ks], kf[j], s[i][j], 0, 0, 0);
            }
            // ---- bias (one float4/step) + online softmax ----
            int ckb = half * 2 + kb;  // k-chunk index 0..3
#pragma unroll
            for (int i = 0; i < 4; i++) {
#pragma unroll
                for (int r = 0; r < 4; r++) {
                    int q = wq + i * 16 + quad * 4 + r;
                    float4 bv = *(const float4*)(bq + (size_t)q * 256 + ckb * 64 + lr * 4);
                    float v0 = s[i][0][r] + bv.x;
                    float v1 = s[i][1][r] + bv.y;
                    float v2 = s[i][2][r] + bv.z;
                    float v3 = s[i][3][r] + bv.w;
                    float mx = fmaxf(fmaxf(v0, v1), fmaxf(v2, v3));
                    mx = fmaxf(mx, __shfl_xor(mx, 1));
                    mx = fmaxf(mx, __shfl_xor(mx, 2));
                    mx = fmaxf(mx, __shfl_xor(mx, 4));
                    mx = fmaxf(mx, __shfl_xor(mx, 8));
                    float mnew = fmaxf(mrun[i][r], mx);
                    float alpha = __expf(mrun[i][r] - mnew);
                    mrun[i][r] = mnew;
                    v0 = __expf(v0 - mnew);
                    v1 = __expf(v1 - mnew);
                    v2 = __expf(v2 - mnew);
                    v3 = __expf(v3 - mnew);
                    lpart[i][r] = lpart[i][r] * alpha + (v0 + v1 + v2 + v3);
                    s[i][0][r] = v0; s[i][1][r] = v1; s[i][2][r] = v2; s[i][3][r] = v3;
#pragma unroll
                    for (int dj = 0; dj < 4; dj++) o[i][dj][r] *= alpha;
                }
            }
            // ---- P -> wave-private LDS scratch (NO block barrier: same-wave lgkm) ----
            bf16* pqb = (bf16*)pqw;
#pragma unroll
            for (int i = 0; i < 4; i++)
#pragma unroll
                for (int r = 0; r < 4; r++) {
                    int ql = i * 16 + quad * 4 + r;
#pragma unroll
                    for (int j = 0; j < 4; j++) {
                        int col = j * 16 + lr;
                        int ck = col >> 3;
                        pqb[ql * 64 + ((ck ^ (ql & 7)) << 3) + (col & 7)] =
                            (bf16)s[i][j][r];
                    }
                }
            asm volatile("s_waitcnt lgkmcnt(0)" ::: "memory");  // P-writes visible to own reads
            // ---- O += P V ----
#pragma unroll
            for (int ks2 = 0; ks2 < 2; ks2++) {
                bf16x8 pf[4], vf[4];
#pragma unroll
                for (int i = 0; i < 4; i++) {
                    int ql = i * 16 + lr;
                    pf[i] = __builtin_bit_cast(bf16x8,
                        pqw[ql * 8 + (((ks2 << 2) + quad) ^ (ql & 7))]);
                }
#pragma unroll
                for (int dj = 0; dj < 4; dj++) {
                    int d = dj * 16 + lr;
                    int ck = kb * 8 + ks2 * 4 + quad;
                    vf[dj] = __builtin_bit_cast(bf16x8,
                        *(const u32x4*)(Vt32 + d * 64 + ((ck ^ (d & 15)) << 2)));
                }
#pragma unroll
                for (int i = 0; i < 4; i++)
#pragma unroll
                    for (int dj = 0; dj < 4; dj++)
                        o[i][dj] = __builtin_amdgcn_mfma_f32_16x16x32_bf16(
                            pf[i], vf[dj], o[i][dj], 0, 0, 0);
            }
        }
    }

    // ---- finalize: 1/l scale -> wave-private LDS -> coalesced 128B-row stores ----
    bf16* ob = (bf16*)pqw;
#pragma unroll
    for (int i = 0; i < 4; i++)
#pragma unroll
        for (int r = 0; r < 4; r++) {
            float lp = lpart[i][r];
            lp += __shfl_xor(lp, 1);
            lp += __shfl_xor(lp, 2);
            lp += __shfl_xor(lp, 4);
            lp += __shfl_xor(lp, 8);
            float inv = 1.0f / lp;
            int row = i * 16 + quad * 4 + r;
#pragma unroll
            for (int dj = 0; dj < 4; dj++) {
                int col = dj * 16 + lr;
                int ck = col >> 3;
                ob[row * 64 + ((ck ^ (row & 7)) << 3) + (col & 7)] =
                    (bf16)(o[i][dj][r] * inv);
            }
        }
    asm volatile("s_waitcnt lgkmcnt(0)" ::: "memory");  // O-writes visible to own reads
#pragma unroll
    for (int it = 0; it < 8; it++) {
        int c = it * 64 + lane;
        int row = c >> 3, p = c & 7;
        u32x4 v = pqw[row * 8 + (p ^ (row & 7))];
        *(u32x4*)(outp + (size_t)(tok0 + wq + row) * CDIM + h * DH + p * 8) = v;
    }
}

// ---------------- launch ----------------
extern "C" void kernel_launch(void* const* d_in, const int* in_sizes, int n_in,
                              void* d_out, int out_size, void* d_ws, size_t ws_size,
                              hipStream_t stream) {
    const float* x      = (const float*)d_in[0];
    const int*   rpi    = (const int*)d_in[1];
    const float* qkv_w  = (const float*)d_in[2];
    const float* qkv_b  = (const float*)d_in[3];
    const float* proj_w = (const float*)d_in[4];
    const float* proj_b = (const float*)d_in[5];
    const float* rpb    = (const float*)d_in[6];
    const float* ln1g   = (const float*)d_in[7];
    const float* ln1b   = (const float*)d_in[8];
    const float* ln2g   = (const float*)d_in[9];
    const float* ln2b   = (const float*)d_in[10];
    const float* fc1_w  = (const float*)d_in[11];
    const float* fc1_b  = (const float*)d_in[12];
    const float* fc2_w  = (const float*)d_in[13];
    const float* fc2_b  = (const float*)d_in[14];
    float* out = (float*)d_out;
    char* ws = (char*)d_ws;

    // --- fixed region: bf16 transposed weights + fp32 biasq (29,360,128 B) ---
    bf16* qkvT   = (bf16*)(ws);                 // 6,291,456
    bf16* projT  = (bf16*)(ws + 6291456ull);    // 2,097,152
    bf16* fc1T   = (bf16*)(ws + 8388608ull);    // 8,388,608
    bf16* fc2T   = (bf16*)(ws + 16777216ull);   // 8,388,608
    float* biasq = (float*)(ws + 25165824ull);  // 4,194,304
    const size_t fixed_end = 29360128ull;

    // --- adaptive chunk: per-row bytes = 2048 (hbuf) + 8192 (qkv or ff) ---
    long long avail = (long long)ws_size - (long long)fixed_end;
    long long rc = avail / 10240;
    rc &= ~255LL;
    if (rc < 256) rc = 256;
    if (rc > MROWS) rc = MROWS;
    const int Rc = (int)rc;
    bf16* hbuf   = (bf16*)(ws + fixed_end);                        // Rc*1024 bf16
    bf16* bigbuf = (bf16*)(ws + fixed_end + (size_t)Rc * 2048ull); // Rc*3072 or Rc*4096 bf16

    transpose_f32_bf16<<<dim3(3072 / 32, 1024 / 32), 256, 0, stream>>>(qkv_w, qkvT, 1024, 3072);
    transpose_f32_bf16<<<dim3(1024 / 32, 1024 / 32), 256, 0, stream>>>(proj_w, projT, 1024, 1024);
    transpose_f32_bf16<<<dim3(4096 / 32, 1024 / 32), 256, 0, stream>>>(fc1_w, fc1T, 1024, 4096);
    transpose_f32_bf16<<<dim3(1024 / 32, 4096 / 32), 256, 0, stream>>>(fc2_w, fc2T, 4096, 1024);
    biasq_kernel<<<4096, 256, 0, stream>>>(rpi, rpb, biasq);

    // --- phase A: LN1 -> qkv -> attention -> proj + residual ---
    for (int r0 = 0; r0 < MROWS; r0 += Rc) {
        int m = MROWS - r0 < Rc ? MROWS - r0 : Rc;
        ln_kernel<<<m, 256, 0, stream>>>(x + (size_t)r0 * CDIM, ln1g, ln1b, hbuf);
        gemm_bt_kernel<<<dim3(3072 / 256, m / 256), 512, 0, stream>>>(
            hbuf, qkvT, qkv_b, nullptr, bigbuf, 0, m, 3072, 1024, 0);
        attn_mfma<<<(m / 256) * NH, 256, 0, stream>>>(bigbuf, biasq, hbuf, 0);
        gemm_bt_kernel<<<dim3(1024 / 256, m / 256), 512, 0, stream>>>(
            hbuf, projT, proj_b, x + (size_t)r0 * CDIM, out + (size_t)r0 * CDIM, 0,
            m, 1024, 1024, 3);
    }

    // --- phase B: LN2 -> fc1+gelu -> fc2 + residual ---
    for (int r0 = 0; r0 < MROWS; r0 += Rc) {
        int m = MROWS - r0 < Rc ? MROWS - r0 : Rc;
        ln_kernel<<<m, 256, 0, stream>>>(out + (size_t)r0 * CDIM, ln2g, ln2b, hbuf);
        gemm_bt_kernel<<<dim3(4096 / 256, m / 256), 512, 0, stream>>>(
            hbuf, fc1T, fc1_b, nullptr, bigbuf, 0, m, 4096, 1024, 2);
        gemm_bt_kernel<<<dim3(1024 / 256, m / 256), 512, 0, stream>>>(
            bigbuf, fc2T, fc2_b, out + (size_t)r0 * CDIM, out + (size_t)r0 * CDIM, 0,
            m, 1024, 4096, 3);
    }
}